// Round 14
// baseline (430.786 us; speedup 1.0000x reference)
//
#include <hip/hip_runtime.h>
#include <math.h>

#define HW 4096
#define IMG 64
#define PIX66 (66 * 66)

typedef short short8 __attribute__((ext_vector_type(8)));
typedef float f32x4 __attribute__((ext_vector_type(4)));

__device__ __forceinline__ unsigned short f2bf(float f) {
    unsigned int u = __float_as_uint(f);
    u += 0x7fff + ((u >> 16) & 1);
    return (unsigned short)(u >> 16);
}
__device__ __forceinline__ float bf2f(unsigned short h) {
    return __uint_as_float(((unsigned int)h) << 16);
}
// pack two fp32 -> bf16 pair (round-half-up), 3 VALU ops
__device__ __forceinline__ unsigned int pkbf(float a, float b) {
    unsigned int ua = __float_as_uint(a) + 0x8000u;
    unsigned int ub = __float_as_uint(b) + 0x8000u;
    return __builtin_amdgcn_perm(ub, ua, 0x07060302u);
}

// async global->LDS, 16B per lane
__device__ __forceinline__ void gll16(const unsigned short* g, unsigned short* l) {
    __builtin_amdgcn_global_load_lds(
        (const __attribute__((address_space(1))) unsigned int*)(g),
        (__attribute__((address_space(3))) unsigned int*)(l), 16, 0, 0);
}

// P32 plane swizzle: chunk index xor'ed per-pixel so conv_lds LDS reads are 2-way
__device__ __forceinline__ int pxor(int pix) { return (pix ^ (pix >> 2)) & 3; }
__device__ __forceinline__ int p32o(int pix, int c) {   // offset in a [PIX66][32] plane
    return pix * 32 + ((((c >> 3) ^ pxor(pix)) & 3) << 3) + (c & 7);
}

// ---------------------------------------------------------------------------
// weight transform: w fp32 [OC][C0+C1][9] -> wT bf16 [9][KS][OCpad][32]
// ---------------------------------------------------------------------------
struct WtJob {
    const float* w;
    unsigned short* dh;
    unsigned short* dl;
    int OC, OCpad, C0, K0pad, C1, Ktot;
};

__global__ __launch_bounds__(256) void k_wt_all(WtJob J0, WtJob J1, WtJob J2,
                                                WtJob J3, WtJob J4, WtJob J5,
                                                WtJob J6) {
    WtJob J;
    switch (blockIdx.y) {
        case 0: J = J0; break;
        case 1: J = J1; break;
        case 2: J = J2; break;
        case 3: J = J3; break;
        case 4: J = J4; break;
        case 5: J = J5; break;
        default: J = J6; break;
    }
    int idx = blockIdx.x * 256 + threadIdx.x;
    int KS = J.Ktot >> 5;
    int n = 9 * KS * J.OCpad * 32;
    if (idx >= n) return;
    int kk = idx & 31;
    int rest = idx >> 5;
    int oc = rest % J.OCpad;
    rest /= J.OCpad;
    int kg = rest % KS;
    int tap = rest / KS;
    int k = kg * 32 + kk;
    float v = 0.f;
    if (oc < J.OC) {
        int ic = -1;
        if (k < J.C0) ic = k;
        else if (k >= J.K0pad && (k - J.K0pad) < J.C1) ic = J.C0 + (k - J.K0pad);
        if (ic >= 0) v = J.w[((size_t)oc * (J.C0 + J.C1) + ic) * 9 + tap];
    }
    unsigned short hi = f2bf(v);
    J.dh[idx] = hi;
    if (J.dl) J.dl[idx] = f2bf(v - bf2f(hi));
}

// ---------------------------------------------------------------------------
// build swizzled P32 bf16 x (hi+lo) [b][8][PIX66][32] and ipad [b][10][PIX66][32]
// ---------------------------------------------------------------------------
__global__ __launch_bounds__(256) void k_build_x(const float* __restrict__ x,
                                                 unsigned short* __restrict__ xh,
                                                 unsigned short* __restrict__ xl,
                                                 unsigned short* __restrict__ ipad) {
    int b = blockIdx.z, c0 = blockIdx.y * 64, p0 = blockIdx.x * 64;
    __shared__ float s[64][65];
    int t = threadIdx.x;
    for (int i = t; i < 4096; i += 256) {
        int c = i >> 6, p = i & 63;
        s[p][c] = x[((size_t)b * 256 + c0 + c) * HW + p0 + p];
    }
    __syncthreads();
    for (int i = t; i < 4096; i += 256) {
        int c = i & 63, p = i >> 6;
        float f = s[p][c];
        unsigned short hi = f2bf(f);
        unsigned short lo = f2bf(f - bf2f(hi));
        int pp = p0 + p;
        int y = pp >> 6, xx = pp & 63;
        int pix = (y + 1) * 66 + xx + 1;
        int C = c0 + c;
        size_t ix = (size_t)(b * 8 + (C >> 5)) * (PIX66 * 32) + p32o(pix, C & 31);
        xh[ix] = hi;
        xl[ix] = lo;
        ipad[(size_t)(b * 10 + (C >> 5)) * (PIX66 * 32) + p32o(pix, C & 31)] = hi;
    }
}

__global__ __launch_bounds__(256) void k_build_mask2(
    const float* __restrict__ m0, const float* __restrict__ m1,
    unsigned short* __restrict__ d0h, unsigned short* __restrict__ d0l,
    unsigned short* __restrict__ d1h, unsigned short* __restrict__ d1l) {
    const float* m = blockIdx.y ? m1 : m0;
    unsigned short* dh = blockIdx.y ? d1h : d0h;
    unsigned short* dl = blockIdx.y ? d1l : d0l;
    int idx = blockIdx.x * 256 + threadIdx.x;   // 2*4096*32
    int c = idx & 31;
    int p = (idx >> 5) & 4095;
    int b = idx >> 17;
    float f = (c < 19) ? m[((size_t)b * 19 + c) * HW + p] : 0.f;
    unsigned short hi = f2bf(f);
    int y = p >> 6, xx = p & 63;
    int pix = (y + 1) * 66 + xx + 1;
    dh[(size_t)b * (PIX66 * 32) + p32o(pix, c)] = hi;
    dl[(size_t)b * (PIX66 * 32) + p32o(pix, c)] = f2bf(f - bf2f(hi));
}

// ---------------------------------------------------------------------------
// fused direct-load MFMA conv: mp/ap/q/k in ONE dispatch (blockIdx.y = job).
// ---------------------------------------------------------------------------
struct DJob {
    const unsigned short* s1h;
    const unsigned short* s1l;
    const unsigned short* wth;
    const unsigned short* wtl;
    const float* bias;
    unsigned short* d1;
    unsigned short* d2;
    const float* mask;
    int chBase;
    int mode;    // 1 or 2
    int split;   // 0 or 1
    int KS1;     // extra K-groups from s1 (0 or 1)
};

__global__ __launch_bounds__(128, 2) void conv_direct_all(
    const unsigned short* __restrict__ s0h, const unsigned short* __restrict__ s0l,
    DJob j0, DJob j1, DJob j2, DJob j3) {
    DJob J;
    switch (blockIdx.y) {
        case 0: J = j0; break;
        case 1: J = j1; break;
        case 2: J = j2; break;
        default: J = j3; break;
    }
    const int KS0 = 8;
    int KS = KS0 + J.KS1;
    int ST = 9 * KS;
    int b = blockIdx.z;
    int t = threadIdx.x, w = t >> 6, l = t & 63, quad = l >> 4, ln = l & 15;
    int pBase = blockIdx.x * 64 + w * 32;

    int padpix[2];
#pragma unroll
    for (int tn = 0; tn < 2; ++tn) {
        int p = pBase + tn * 16 + ln;
        padpix[tn] = ((p >> 6) + 1) * 66 + (p & 63) + 1;
    }
    size_t aoff[2];
#pragma unroll
    for (int tm = 0; tm < 2; ++tm) aoff[tm] = (size_t)(tm * 16 + ln) * 32 + quad * 8;

    const unsigned short* S0H = s0h + (size_t)b * KS0 * PIX66 * 32;
    const unsigned short* S0L = s0l + (size_t)b * KS0 * PIX66 * 32;
    const unsigned short* S1H = J.KS1 ? J.s1h + (size_t)b * PIX66 * 32
                                      : (const unsigned short*)0;
    const unsigned short* S1L = J.KS1 ? J.s1l + (size_t)b * PIX66 * 32
                                      : (const unsigned short*)0;

    f32x4 acc[2][2];
#pragma unroll
    for (int i = 0; i < 2; ++i)
#pragma unroll
        for (int j = 0; j < 2; ++j) acc[i][j] = (f32x4){0.f, 0.f, 0.f, 0.f};

    int tap = 0, kg = 0;
    auto adv = [&]() { if (++kg == KS) { kg = 0; ++tap; } };
    auto loadStep = [&](int ltap, int lkg, short8* bh, short8* bl, short8* ah,
                        short8* al) {
        int d3 = ltap / 3;
        int dpix = (d3 - 1) * 66 + (ltap - d3 * 3 - 1);
        const unsigned short* SpH;
        const unsigned short* SpL;
        long plane;
        if (lkg < KS0) {
            SpH = S0H; SpL = S0L; plane = (long)lkg * PIX66 * 32;
        } else {
            SpH = S1H; SpL = S1L; plane = 0;
        }
#pragma unroll
        for (int tn = 0; tn < 2; ++tn) {
            int pix2 = padpix[tn] + dpix;
            long off = plane + (long)pix2 * 32 + (((quad ^ pxor(pix2)) & 3) << 3);
            bh[tn] = *(const short8*)(SpH + off);
            if (J.split) bl[tn] = *(const short8*)(SpL + off);
        }
        const unsigned short* WTh = J.wth + (size_t)(ltap * KS + lkg) * 32 * 32;
        ah[0] = *(const short8*)(WTh + aoff[0]);
        ah[1] = *(const short8*)(WTh + aoff[1]);
        if (J.split) {
            const unsigned short* WTl = J.wtl + (size_t)(ltap * KS + lkg) * 32 * 32;
            al[0] = *(const short8*)(WTl + aoff[0]);
            al[1] = *(const short8*)(WTl + aoff[1]);
        }
    };

    short8 BH[2][2], AH[2][2], BL[2][2], AL[2][2];
#pragma unroll
    for (int u = 0; u < 2; ++u) { loadStep(tap, kg, BH[u], BL[u], AH[u], AL[u]); adv(); }

    for (int s = 0; s < ST; s += 2) {
#pragma unroll
        for (int u = 0; u < 2; ++u) {
            if (s + u < ST) {
#pragma unroll
                for (int tm = 0; tm < 2; ++tm)
#pragma unroll
                    for (int tn = 0; tn < 2; ++tn) {
                        acc[tm][tn] = __builtin_amdgcn_mfma_f32_16x16x32_bf16(
                            AH[u][tm], BH[u][tn], acc[tm][tn], 0, 0, 0);
                        if (J.split) {
                            acc[tm][tn] = __builtin_amdgcn_mfma_f32_16x16x32_bf16(
                                AL[u][tm], BH[u][tn], acc[tm][tn], 0, 0, 0);
                            acc[tm][tn] = __builtin_amdgcn_mfma_f32_16x16x32_bf16(
                                AH[u][tm], BL[u][tn], acc[tm][tn], 0, 0, 0);
                        }
                    }
                if (s + u + 2 < ST) { loadStep(tap, kg, BH[u], BL[u], AH[u], AL[u]); adv(); }
            }
        }
    }

#pragma unroll
    for (int tm = 0; tm < 2; ++tm) {
#pragma unroll
        for (int r = 0; r < 4; ++r) {
            int oc = tm * 16 + quad * 4 + r;
#pragma unroll
            for (int tn = 0; tn < 2; ++tn) {
                int p = pBase + tn * 16 + ln;
                if (J.mode == 1) {
                    if (oc < 19) {
                        float v = (acc[tm][tn][r] + J.bias[oc]) *
                                  J.mask[((size_t)b * 19 + oc) * HW + p];
                        int ch = J.chBase + oc;
                        J.d1[(size_t)(b * 10 + (ch >> 5)) * (PIX66 * 32) +
                             p32o(padpix[tn], ch & 31)] = f2bf(v);
                    }
                } else {  // mode 2
                    float v = acc[tm][tn][r] + J.bias[oc];
                    unsigned short hi = f2bf(v);
                    J.d1[((size_t)b * HW + p) * 32 + oc] = hi;
                    J.d2[((size_t)b * HW + p) * 32 + oc] = f2bf(v - bf2f(hi));
                }
            }
        }
    }
}

// ---------------------------------------------------------------------------
// K-split LDS-staged MFMA conv (v / comp / out) -> partials.
// atomicOut: atomicAdd fp32 into dstf[b][oc][HW] (out conv; dst pre-init w/ bias)
// else dstb16: bf16 partials [z][oc][HW]
// ---------------------------------------------------------------------------
struct LJob {
    const unsigned short* src;   // [B][KS][PIX66][32] swizzled
    const unsigned short* wt;    // [9][KS][256][32]
    float* dstf;
    unsigned short* dstb16;
    int KS;
    int nseg;
    int doSum;
    int atomicOut;
};

__global__ __launch_bounds__(128, 3) void conv_lds(LJob j0, LJob j1, int ocgPerJob,
                                                   float* __restrict__ ybuf) {
    int jy = blockIdx.y;
    LJob J = (jy >= ocgPerJob) ? j1 : j0;
    int ocBase = ((jy >= ocgPerJob) ? jy - ocgPerJob : jy) * 64;
    int z = blockIdx.z;
    int b = z & 1, seg = z >> 1;
    int kgPer = J.KS / J.nseg;
    int kgBeg = seg * kgPer, kgEnd = kgBeg + kgPer;
    int ry = blockIdx.x * 2;
    int t = threadIdx.x, w = t >> 6, l = t & 63, quad = l >> 4, ln = l & 15;

    __shared__ unsigned short sB[2][264 * 32];

    const unsigned short* S = J.src + (size_t)b * J.KS * PIX66 * 32;
    const size_t bStageBase = (size_t)(ry * 66) * 32;

    f32x4 acc[4][4];
#pragma unroll
    for (int i = 0; i < 4; ++i)
#pragma unroll
        for (int j = 0; j < 4; ++j) acc[i][j] = (f32x4){0.f, 0.f, 0.f, 0.f};

    {
        const unsigned short* gB = S + (size_t)kgBeg * PIX66 * 32 + bStageBase;
        for (int i = t; i < 1056; i += 128) gll16(gB + (size_t)i * 8, sB[0] + (size_t)i * 8);
    }

    for (int kg = kgBeg; kg < kgEnd; ++kg) {
        int cur = (kg - kgBeg) & 1;
        __syncthreads();
        if (kg + 1 < kgEnd) {
            const unsigned short* gB = S + (size_t)(kg + 1) * PIX66 * 32 + bStageBase;
            for (int i = t; i < 1056; i += 128)
                gll16(gB + (size_t)i * 8, sB[cur ^ 1] + (size_t)i * 8);
        }
        const unsigned short* sBc = sB[cur];
#pragma unroll
        for (int tap = 0; tap < 9; ++tap) {
            const unsigned short* gA =
                J.wt + ((size_t)(tap * J.KS + kg) * 256 + ocBase) * 32;
            int dy = tap / 3 - 1, dx = tap % 3 - 1;
            int lpBase = (1 + w + dy) * 66 + 1 + dx;
            short8 bf[4], af[4];
#pragma unroll
            for (int tn = 0; tn < 4; ++tn) {
                int lp = lpBase + tn * 16 + ln;
                int P = ry * 66 + lp;
                bf[tn] = *(const short8*)(sBc + (size_t)lp * 32 +
                                          (((quad ^ pxor(P)) & 3) << 3));
            }
#pragma unroll
            for (int tm = 0; tm < 4; ++tm)
                af[tm] = *(const short8*)(gA + (size_t)(tm * 16 + ln) * 32 + quad * 8);
#pragma unroll
            for (int tm = 0; tm < 4; ++tm)
#pragma unroll
                for (int tn = 0; tn < 4; ++tn)
                    acc[tm][tn] = __builtin_amdgcn_mfma_f32_16x16x32_bf16(
                        af[tm], bf[tn], acc[tm][tn], 0, 0, 0);
        }
    }

    int prow = ry + w;
#pragma unroll
    for (int tm = 0; tm < 4; ++tm) {
#pragma unroll
        for (int r = 0; r < 4; ++r) {
            int oc = ocBase + tm * 16 + quad * 4 + r;
            float msum = 0.f;
#pragma unroll
            for (int tn = 0; tn < 4; ++tn) {
                int px = tn * 16 + ln;
                if (J.atomicOut) {
                    atomicAdd(&J.dstf[((size_t)b * 256 + oc) * HW + prow * 64 + px],
                              acc[tm][tn][r]);
                } else if (J.dstb16) {
                    J.dstb16[((size_t)z * 256 + oc) * HW + prow * 64 + px] =
                        f2bf(acc[tm][tn][r]);
                    msum += acc[tm][tn][r];
                }
            }
            if (J.doSum) {
#pragma unroll
                for (int off = 8; off; off >>= 1) msum += __shfl_down(msum, off, 16);
                if (ln == 0) atomicAdd(&ybuf[b * 256 + oc], msum);
            }
        }
    }
}

// d_out = bias (per-channel broadcast), NCHW
__global__ __launch_bounds__(256) void out_init(const float* __restrict__ bias,
                                                float* __restrict__ outp) {
    int idx = blockIdx.x * 256 + threadIdx.x;   // 2*256*4096
    int oc = (idx >> 12) & 255;
    outp[idx] = bias[oc];
}

// merged: vt = segsum(pV16)+b_v (key-major swizzled bf16)
//         catN ch0..255 = (segsum(pC16)+b_comp)*sc
__global__ __launch_bounds__(256) void vc_combine(
    const unsigned short* __restrict__ pV, const float* __restrict__ bv,
    unsigned short* __restrict__ vt,
    const unsigned short* __restrict__ pC, const float* __restrict__ bc,
    const float* __restrict__ sc, unsigned short* __restrict__ catN) {
    int idx = blockIdx.x * 256 + threadIdx.x;   // 2*256*4096
    int p = idx & 4095;
    int oc = (idx >> 12) & 255;
    int b = idx >> 20;
    int prow = p >> 6, px = p & 63;
    float v = bf2f(pV[((size_t)b * 256 + oc) * HW + p]) +
              bf2f(pV[((size_t)(2 + b) * 256 + oc) * HW + p]) + bv[oc];
    int jc = ((px >> 3) ^ (oc & 7)) & 7;
    vt[(((size_t)b * 64 + prow) * 256 + oc) * 64 + jc * 8 + (px & 7)] = f2bf(v);
    float c = (bf2f(pC[((size_t)b * 256 + oc) * HW + p]) +
               bf2f(pC[((size_t)(2 + b) * 256 + oc) * HW + p]) + bc[oc]) *
              sc[b * 256 + oc];
    int pix = (prow + 1) * 66 + px + 1;
    catN[(size_t)(b * 24 + (oc >> 5)) * (PIX66 * 32) + p32o(pix, oc & 31)] = f2bf(c);
}

// ---------------------------------------------------------------------------
// Flash attention v3 internals, key-split NSEG=2; partial O as bf16.
// ---------------------------------------------------------------------------
__global__ __launch_bounds__(512, 4) void flash_attn(
    const unsigned short* __restrict__ qt_h, const unsigned short* __restrict__ qt_l,
    const unsigned short* __restrict__ kt_h, const unsigned short* __restrict__ kt_l,
    const unsigned short* __restrict__ vt,
    unsigned short* __restrict__ pO, float* __restrict__ pm, float* __restrict__ pl) {
    int seg = blockIdx.y >> 1, mode = blockIdx.y & 1, b = blockIdx.z;
    size_t qkoff = (size_t)b * HW * 32;
    const unsigned short* Qh = (mode ? kt_h : qt_h) + qkoff;
    const unsigned short* Ql = (mode ? kt_l : qt_l) + qkoff;
    const unsigned short* Kh = (mode ? qt_h : kt_h) + qkoff;
    const unsigned short* Kl = (mode ? qt_l : kt_l) + qkoff;
    const unsigned short* Vt = vt + (size_t)b * 64 * 256 * 64;

    int t = threadIdx.x, w = t >> 6, l = t & 63, quad = l >> 4, ln = l & 15;
    int pg = w & 1, ch = w >> 1;
    int p0 = blockIdx.x * 64, pw = pg * 32;
    int cb = ch * 64;
    bool soft = (ch == (pg ? 3 : 0));

    __shared__ unsigned short sV[256 * 64];
    __shared__ unsigned short sP[64 * 68];
    __shared__ float sAl[64];

    short8 qbh[2], qbl[2];
    if (soft) {
#pragma unroll
        for (int pn = 0; pn < 2; ++pn) {
            size_t off = (size_t)(p0 + pw + pn * 16 + ln) * 32 + quad * 8;
            qbh[pn] = *(const short8*)(Qh + off);
            qbl[pn] = *(const short8*)(Ql + off);
        }
    }

    float m_run[2] = {-3.0e38f, -3.0e38f};
    float l_run[2] = {0.f, 0.f};
    f32x4 accO[4][2];
#pragma unroll
    for (int cs = 0; cs < 4; ++cs)
#pragma unroll
        for (int pn = 0; pn < 2; ++pn) accO[cs][pn] = (f32x4){0.f, 0.f, 0.f, 0.f};

    int jbBeg = seg * (HW / 2);
    for (int jb = jbBeg; jb < jbBeg + HW / 2; jb += 64) {
        __syncthreads();
        {
            const unsigned short* gV = Vt + (size_t)(jb >> 6) * (256 * 64);
#pragma unroll
            for (int i = 0; i < 4; ++i)
                gll16(gV + (size_t)(t + 512 * i) * 8, sV + (size_t)(t + 512 * i) * 8);
        }
        if (soft) {
            f32x4 sacc[2][4];
#pragma unroll
            for (int pn = 0; pn < 2; ++pn)
#pragma unroll
                for (int jj = 0; jj < 4; ++jj) sacc[pn][jj] = (f32x4){0.f, 0.f, 0.f, 0.f};
#pragma unroll
            for (int jj = 0; jj < 4; ++jj) {
                size_t off = (size_t)(jb + 16 * jj + ln) * 32 + quad * 8;
                short8 kh = *(const short8*)(Kh + off);
                short8 kr = *(const short8*)(Kl + off);
#pragma unroll
                for (int pn = 0; pn < 2; ++pn) {
                    sacc[pn][jj] = __builtin_amdgcn_mfma_f32_16x16x32_bf16(
                        kh, qbh[pn], sacc[pn][jj], 0, 0, 0);
                    sacc[pn][jj] = __builtin_amdgcn_mfma_f32_16x16x32_bf16(
                        kh, qbl[pn], sacc[pn][jj], 0, 0, 0);
                    sacc[pn][jj] = __builtin_amdgcn_mfma_f32_16x16x32_bf16(
                        kr, qbh[pn], sacc[pn][jj], 0, 0, 0);
                }
            }
#pragma unroll
            for (int pn = 0; pn < 2; ++pn) {
                float tmx = -3.0e38f;
#pragma unroll
                for (int jj = 0; jj < 4; ++jj)
#pragma unroll
                    for (int r = 0; r < 4; ++r) tmx = fmaxf(tmx, sacc[pn][jj][r]);
                tmx = fmaxf(tmx, __shfl_xor(tmx, 16));
                tmx = fmaxf(tmx, __shfl_xor(tmx, 32));
                float mnew = fmaxf(m_run[pn], tmx);
                float alpha = __expf(m_run[pn] - mnew);
                m_run[pn] = mnew;
                float psum = 0.f;
#pragma unroll
                for (int jj = 0; jj < 4; ++jj) {
                    float e0 = __expf(sacc[pn][jj][0] - mnew);
                    float e1 = __expf(sacc[pn][jj][1] - mnew);
                    float e2 = __expf(sacc[pn][jj][2] - mnew);
                    float e3 = __expf(sacc[pn][jj][3] - mnew);
                    psum += (e0 + e1) + (e2 + e3);
                    uint2 pk;
                    pk.x = pkbf(e0, e1);
                    pk.y = pkbf(e2, e3);
                    *(uint2*)(sP + (size_t)(pw + pn * 16 + ln) * 68 + jj * 16 +
                              quad * 4) = pk;
                }
                psum += __shfl_xor(psum, 16);
                psum += __shfl_xor(psum, 32);
                l_run[pn] = l_run[pn] * alpha + psum;
                if (quad == 0) sAl[pw + pn * 16 + ln] = alpha;
            }
        }
        __syncthreads();
        float al0 = sAl[pw + ln];
        float al1 = sAl[pw + 16 + ln];
#pragma unroll
        for (int cs = 0; cs < 4; ++cs) { accO[cs][0] *= al0; accO[cs][1] *= al1; }
#pragma unroll
        for (int j2 = 0; j2 < 2; ++j2) {
            short8 pb0 = *(const short8*)(sP + (size_t)(pw + ln) * 68 + j2 * 32 +
                                          quad * 8);
            short8 pb1 = *(const short8*)(sP + (size_t)(pw + 16 + ln) * 68 + j2 * 32 +
                                          quad * 8);
#pragma unroll
            for (int cs = 0; cs < 4; ++cs) {
                int c = cb + cs * 16 + ln;
                short8 va = *(const short8*)(
                    sV + (size_t)c * 64 + ((((j2 * 4 + quad) ^ (c & 7)) & 7) << 3));
                accO[cs][0] = __builtin_amdgcn_mfma_f32_16x16x32_bf16(
                    va, pb0, accO[cs][0], 0, 0, 0);
                accO[cs][1] = __builtin_amdgcn_mfma_f32_16x16x32_bf16(
                    va, pb1, accO[cs][1], 0, 0, 0);
            }
        }
    }

    int idx4 = (seg * 2 + mode) * 2 + b;
#pragma unroll
    for (int pn = 0; pn < 2; ++pn) {
        int p = p0 + pw + pn * 16 + ln;
        if (soft && quad == 0) {
            pm[(size_t)idx4 * HW + p] = m_run[pn];
            pl[(size_t)idx4 * HW + p] = l_run[pn];
        }
#pragma unroll
        for (int cs = 0; cs < 4; ++cs)
#pragma unroll
            for (int r = 0; r < 4; ++r) {
                int c = cb + cs * 16 + quad * 4 + r;
                pO[((size_t)idx4 * 256 + c) * HW + p] = f2bf(accO[cs][pn][r]);
            }
    }
}

// combine two key-segments (bf16 partials) -> catN ch 256+mode*256..
__global__ __launch_bounds__(256) void attn_combine(const unsigned short* __restrict__ pO,
                                                    const float* __restrict__ pm,
                                                    const float* __restrict__ pl,
                                                    unsigned short* __restrict__ catN) {
    int b = blockIdx.z, mode = blockIdx.y;
    int t = threadIdx.x;
    int p = blockIdx.x * 64 + (t & 63);
    int c0 = (t >> 6) * 64;
    int i0 = mode * 2 + b;
    int i1 = 4 + mode * 2 + b;
    float m0 = pm[(size_t)i0 * HW + p], m1 = pm[(size_t)i1 * HW + p];
    float l0 = pl[(size_t)i0 * HW + p], l1 = pl[(size_t)i1 * HW + p];
    float M = fmaxf(m0, m1);
    float e0 = __expf(m0 - M), e1 = __expf(m1 - M);
    float inv = 1.f / (l0 * e0 + l1 * e1);
    e0 *= inv;
    e1 *= inv;
    int y = p >> 6, x = p & 63;
    int pix = (y + 1) * 66 + x + 1;
    for (int c = c0; c < c0 + 64; ++c) {
        float v = bf2f(pO[((size_t)i0 * 256 + c) * HW + p]) * e0 +
                  bf2f(pO[((size_t)i1 * 256 + c) * HW + p]) * e1;
        int cf = 256 + mode * 256 + c;
        catN[(size_t)(b * 24 + (cf >> 5)) * (PIX66 * 32) + p32o(pix, cf & 31)] = f2bf(v);
    }
}

// ---------------------------------------------------------------------------
// SE mlp (bias folded: y = rawsum/4096 + b_comp)
// ---------------------------------------------------------------------------
__global__ __launch_bounds__(256) void se_mlp_kernel(const float* __restrict__ y,
                                                     const float* __restrict__ bcomp,
                                                     const float* __restrict__ w1,
                                                     const float* __restrict__ w2,
                                                     float* __restrict__ sc) {
    int b = blockIdx.x, t = threadIdx.x;
    __shared__ float sy[256], sh[32];
    sy[t] = y[b * 256 + t] * (1.f / 4096.f) + bcomp[t];
    __syncthreads();
    if (t < 32) {
        float s = 0.f;
        for (int c = 0; c < 256; ++c) s = fmaf(w1[t * 256 + c], sy[c], s);
        sh[t] = fmaxf(s, 0.f);
    }
    __syncthreads();
    float s = 0.f;
#pragma unroll
    for (int h = 0; h < 32; ++h) s = fmaf(w2[t * 32 + h], sh[h], s);
    sc[b * 256 + t] = 1.f / (1.f + __expf(-s));
}

// ---------------------------------------------------------------------------
extern "C" void kernel_launch(void* const* d_in, const int* in_sizes, int n_in,
                              void* d_out, int out_size, void* d_ws, size_t ws_size,
                              hipStream_t stream) {
    const float* x      = (const float*)d_in[0];
    const float* mmask  = (const float*)d_in[1];
    const float* amask  = (const float*)d_in[2];
    const float* w_mp   = (const float*)d_in[3];
    const float* b_mp   = (const float*)d_in[4];
    const float* w_ap   = (const float*)d_in[5];
    const float* b_ap   = (const float*)d_in[6];
    const float* w_q    = (const float*)d_in[7];
    const float* b_q    = (const float*)d_in[8];
    const float* w_k    = (const float*)d_in[9];
    const float* b_k    = (const float*)d_in[10];
    const float* w_v    = (const float*)d_in[11];
    const float* b_v    = (const float*)d_in[12];
    const float* w_comp = (const float*)d_in[13];
    const float* b_comp = (const float*)d_in[14];
    const float* w_out  = (const float*)d_in[15];
    const float* b_out  = (const float*)d_in[16];
    const float* w_se1  = (const float*)d_in[17];
    const float* w_se2  = (const float*)d_in[18];

    unsigned short* us = (unsigned short*)d_ws;
    size_t o = 0;
    // ---- zeroed bf16 region (swizzled P32 padded buffers) ----
    unsigned short* xpad_hi = us + o; o += (size_t)2 * 8 * PIX66 * 32;
    unsigned short* xpad_lo = us + o; o += (size_t)2 * 8 * PIX66 * 32;
    unsigned short* mq_hi   = us + o; o += (size_t)2 * PIX66 * 32;
    unsigned short* mq_lo   = us + o; o += (size_t)2 * PIX66 * 32;
    unsigned short* ma_hi   = us + o; o += (size_t)2 * PIX66 * 32;
    unsigned short* ma_lo   = us + o; o += (size_t)2 * PIX66 * 32;
    unsigned short* ipad    = us + o; o += (size_t)2 * 10 * PIX66 * 32;
    unsigned short* catN    = us + o; o += (size_t)2 * 24 * PIX66 * 32;
    size_t zeroBytes = o * sizeof(unsigned short);
    // ---- fully-written bf16 region ----
    unsigned short* wt_mp = us + o; o += (size_t)9 * 8 * 32 * 32;
    unsigned short* wt_ap = us + o; o += (size_t)9 * 8 * 32 * 32;
    unsigned short* wt_qh = us + o; o += (size_t)9 * 9 * 32 * 32;
    unsigned short* wt_ql = us + o; o += (size_t)9 * 9 * 32 * 32;
    unsigned short* wt_kh = us + o; o += (size_t)9 * 9 * 32 * 32;
    unsigned short* wt_kl = us + o; o += (size_t)9 * 9 * 32 * 32;
    unsigned short* wt_v  = us + o; o += (size_t)9 * 8 * 256 * 32;
    unsigned short* wt_cp = us + o; o += (size_t)9 * 10 * 256 * 32;
    unsigned short* wt_ot = us + o; o += (size_t)9 * 24 * 256 * 32;
    unsigned short* qt_h  = us + o; o += (size_t)2 * HW * 32;
    unsigned short* qt_l  = us + o; o += (size_t)2 * HW * 32;
    unsigned short* kt_h  = us + o; o += (size_t)2 * HW * 32;
    unsigned short* kt_l  = us + o; o += (size_t)2 * HW * 32;
    unsigned short* vt    = us + o; o += (size_t)2 * 64 * 256 * 64;
    unsigned short* pV16  = us + o; o += (size_t)4 * 256 * HW;
    unsigned short* pC16  = us + o; o += (size_t)4 * 256 * HW;
    unsigned short* pA16  = us + o; o += (size_t)8 * 256 * HW;
    // ---- fp32 region (fully written before read) ----
    float* fp = (float*)(us + o);
    size_t fo = 0;
    float* pmb  = fp + fo; fo += (size_t)8 * HW;
    float* plb  = fp + fo; fo += (size_t)8 * HW;
    float* ybuf = fp + fo; fo += 512;
    float* sbuf = fp + fo; fo += 512;
    size_t need = o * sizeof(unsigned short) + fo * sizeof(float);
    if (ws_size < need) return;

    float* outp = (float*)d_out;

    hipMemsetAsync(us, 0, zeroBytes, stream);
    hipMemsetAsync(ybuf, 0, 512 * sizeof(float), stream);

    // fused weight transforms
    WtJob W0{w_mp,   wt_mp, (unsigned short*)0, 19, 32, 256, 256, 0, 256};
    WtJob W1{w_ap,   wt_ap, (unsigned short*)0, 19, 32, 256, 256, 0, 256};
    WtJob W2{w_q,    wt_qh, wt_ql,             32, 32, 256, 256, 19, 288};
    WtJob W3{w_k,    wt_kh, wt_kl,             32, 32, 256, 256, 19, 288};
    WtJob W4{w_v,    wt_v,  (unsigned short*)0, 256, 256, 256, 256, 0, 256};
    WtJob W5{w_comp, wt_cp, (unsigned short*)0, 256, 256, 294, 320, 0, 320};
    WtJob W6{w_out,  wt_ot, (unsigned short*)0, 256, 256, 768, 768, 0, 768};
    k_wt_all<<<dim3((9 * 24 * 256 * 32 + 255) / 256, 7), 256, 0, stream>>>(
        W0, W1, W2, W3, W4, W5, W6);

    k_build_x<<<dim3(64, 4, 2), 256, 0, stream>>>(x, xpad_hi, xpad_lo, ipad);
    k_build_mask2<<<dim3(1024, 2), 256, 0, stream>>>(mmask, amask, mq_hi, mq_lo,
                                                     ma_hi, ma_lo);

    const unsigned short* NUS = (const unsigned short*)0;
    unsigned short* NUSo = (unsigned short*)0;
    float* NF = (float*)0;

    // mp+ap+q+k in one dispatch
    DJob dm{NUS, NUS, wt_mp, NUS, b_mp, ipad, NUSo, mmask, 256, 1, 0, 0};
    DJob da{NUS, NUS, wt_ap, NUS, b_ap, ipad, NUSo, amask, 275, 1, 0, 0};
    DJob dq{mq_hi, mq_lo, wt_qh, wt_ql, b_q, qt_h, qt_l, NF, 0, 2, 1, 1};
    DJob dk{ma_hi, ma_lo, wt_kh, wt_kl, b_k, kt_h, kt_l, NF, 0, 2, 1, 1};
    conv_direct_all<<<dim3(64, 4, 2), 128, 0, stream>>>(xpad_hi, xpad_lo, dm, da, dq, dk);

    // v + comp, K-split x2 -> bf16 partials (1024 blocks)
    LJob lv{xpad_hi, wt_v, NF, pV16, 8, 2, 0, 0};
    LJob lc{ipad, wt_cp, NF, pC16, 10, 2, 1, 0};
    conv_lds<<<dim3(32, 8, 4), 128, 0, stream>>>(lv, lc, 4, ybuf);

    // SE (bias folded) + merged v/comp combine (bf16 partial reads)
    se_mlp_kernel<<<2, 256, 0, stream>>>(ybuf, b_comp, w_se1, w_se2, sbuf);
    vc_combine<<<8192, 256, 0, stream>>>(pV16, b_v, vt, pC16, b_comp, sbuf, catN);

    // flash attention (v3 internals), key-split NSEG=2, bf16 partial O
    flash_attn<<<dim3(64, 4, 2), 512, 0, stream>>>(qt_h, qt_l, kt_h, kt_l, vt,
                                                   pA16, pmb, plb);
    attn_combine<<<dim3(64, 2, 2), 256, 0, stream>>>(pA16, pmb, plb, catN);

    // final conv: init d_out with bias, then K-split x4 atomicAdd into d_out
    out_init<<<8192, 256, 0, stream>>>(b_out, outp);
    LJob lo{catN, wt_ot, outp, NUSo, 24, 4, 0, 1};
    conv_lds<<<dim3(32, 4, 8), 128, 0, stream>>>(lo, lo, 4, NF);
}

// Round 15
// 413.246 us; speedup vs baseline: 1.0424x; 1.0424x over previous
//
#include <hip/hip_runtime.h>
#include <math.h>

#define HW 4096
#define IMG 64
#define PIX66 (66 * 66)

typedef short short8 __attribute__((ext_vector_type(8)));
typedef float f32x4 __attribute__((ext_vector_type(4)));

__device__ __forceinline__ unsigned short f2bf(float f) {
    unsigned int u = __float_as_uint(f);
    u += 0x7fff + ((u >> 16) & 1);
    return (unsigned short)(u >> 16);
}
__device__ __forceinline__ float bf2f(unsigned short h) {
    return __uint_as_float(((unsigned int)h) << 16);
}
// pack two fp32 -> bf16 pair (round-half-up), 3 VALU ops
__device__ __forceinline__ unsigned int pkbf(float a, float b) {
    unsigned int ua = __float_as_uint(a) + 0x8000u;
    unsigned int ub = __float_as_uint(b) + 0x8000u;
    return __builtin_amdgcn_perm(ub, ua, 0x07060302u);
}

// async global->LDS, 16B per lane
__device__ __forceinline__ void gll16(const unsigned short* g, unsigned short* l) {
    __builtin_amdgcn_global_load_lds(
        (const __attribute__((address_space(1))) unsigned int*)(g),
        (__attribute__((address_space(3))) unsigned int*)(l), 16, 0, 0);
}

// P32 plane swizzle: chunk index xor'ed per-pixel so conv_lds LDS reads are 2-way
__device__ __forceinline__ int pxor(int pix) { return (pix ^ (pix >> 2)) & 3; }
__device__ __forceinline__ int p32o(int pix, int c) {   // offset in a [PIX66][32] plane
    return pix * 32 + ((((c >> 3) ^ pxor(pix)) & 3) << 3) + (c & 7);
}

// ---------------------------------------------------------------------------
// weight transform: w fp32 [OC][C0+C1][9] -> wT bf16 [9][KS][OCpad][32]
// ---------------------------------------------------------------------------
struct WtJob {
    const float* w;
    unsigned short* dh;
    unsigned short* dl;
    int OC, OCpad, C0, K0pad, C1, Ktot;
};

__global__ __launch_bounds__(256) void k_wt_all(WtJob J0, WtJob J1, WtJob J2,
                                                WtJob J3, WtJob J4, WtJob J5,
                                                WtJob J6) {
    WtJob J;
    switch (blockIdx.y) {
        case 0: J = J0; break;
        case 1: J = J1; break;
        case 2: J = J2; break;
        case 3: J = J3; break;
        case 4: J = J4; break;
        case 5: J = J5; break;
        default: J = J6; break;
    }
    int idx = blockIdx.x * 256 + threadIdx.x;
    int KS = J.Ktot >> 5;
    int n = 9 * KS * J.OCpad * 32;
    if (idx >= n) return;
    int kk = idx & 31;
    int rest = idx >> 5;
    int oc = rest % J.OCpad;
    rest /= J.OCpad;
    int kg = rest % KS;
    int tap = rest / KS;
    int k = kg * 32 + kk;
    float v = 0.f;
    if (oc < J.OC) {
        int ic = -1;
        if (k < J.C0) ic = k;
        else if (k >= J.K0pad && (k - J.K0pad) < J.C1) ic = J.C0 + (k - J.K0pad);
        if (ic >= 0) v = J.w[((size_t)oc * (J.C0 + J.C1) + ic) * 9 + tap];
    }
    unsigned short hi = f2bf(v);
    J.dh[idx] = hi;
    if (J.dl) J.dl[idx] = f2bf(v - bf2f(hi));
}

// ---------------------------------------------------------------------------
// build swizzled P32 bf16 x (hi+lo) [b][8][PIX66][32] and ipad [b][10][PIX66][32]
// ---------------------------------------------------------------------------
__global__ __launch_bounds__(256) void k_build_x(const float* __restrict__ x,
                                                 unsigned short* __restrict__ xh,
                                                 unsigned short* __restrict__ xl,
                                                 unsigned short* __restrict__ ipad) {
    int b = blockIdx.z, c0 = blockIdx.y * 64, p0 = blockIdx.x * 64;
    __shared__ float s[64][65];
    int t = threadIdx.x;
    for (int i = t; i < 4096; i += 256) {
        int c = i >> 6, p = i & 63;
        s[p][c] = x[((size_t)b * 256 + c0 + c) * HW + p0 + p];
    }
    __syncthreads();
    for (int i = t; i < 4096; i += 256) {
        int c = i & 63, p = i >> 6;
        float f = s[p][c];
        unsigned short hi = f2bf(f);
        unsigned short lo = f2bf(f - bf2f(hi));
        int pp = p0 + p;
        int y = pp >> 6, xx = pp & 63;
        int pix = (y + 1) * 66 + xx + 1;
        int C = c0 + c;
        size_t ix = (size_t)(b * 8 + (C >> 5)) * (PIX66 * 32) + p32o(pix, C & 31);
        xh[ix] = hi;
        xl[ix] = lo;
        ipad[(size_t)(b * 10 + (C >> 5)) * (PIX66 * 32) + p32o(pix, C & 31)] = hi;
    }
}

__global__ __launch_bounds__(256) void k_build_mask2(
    const float* __restrict__ m0, const float* __restrict__ m1,
    unsigned short* __restrict__ d0h, unsigned short* __restrict__ d0l,
    unsigned short* __restrict__ d1h, unsigned short* __restrict__ d1l) {
    const float* m = blockIdx.y ? m1 : m0;
    unsigned short* dh = blockIdx.y ? d1h : d0h;
    unsigned short* dl = blockIdx.y ? d1l : d0l;
    int idx = blockIdx.x * 256 + threadIdx.x;   // 2*4096*32
    int c = idx & 31;
    int p = (idx >> 5) & 4095;
    int b = idx >> 17;
    float f = (c < 19) ? m[((size_t)b * 19 + c) * HW + p] : 0.f;
    unsigned short hi = f2bf(f);
    int y = p >> 6, xx = p & 63;
    int pix = (y + 1) * 66 + xx + 1;
    dh[(size_t)b * (PIX66 * 32) + p32o(pix, c)] = hi;
    dl[(size_t)b * (PIX66 * 32) + p32o(pix, c)] = f2bf(f - bf2f(hi));
}

// ---------------------------------------------------------------------------
// fused direct-load MFMA conv: mp/ap/q/k in ONE dispatch (blockIdx.y = job).
// ---------------------------------------------------------------------------
struct DJob {
    const unsigned short* s1h;
    const unsigned short* s1l;
    const unsigned short* wth;
    const unsigned short* wtl;
    const float* bias;
    unsigned short* d1;
    unsigned short* d2;
    const float* mask;
    int chBase;
    int mode;    // 1 or 2
    int split;   // 0 or 1
    int KS1;     // extra K-groups from s1 (0 or 1)
};

__global__ __launch_bounds__(128, 2) void conv_direct_all(
    const unsigned short* __restrict__ s0h, const unsigned short* __restrict__ s0l,
    DJob j0, DJob j1, DJob j2, DJob j3) {
    DJob J;
    switch (blockIdx.y) {
        case 0: J = j0; break;
        case 1: J = j1; break;
        case 2: J = j2; break;
        default: J = j3; break;
    }
    const int KS0 = 8;
    int KS = KS0 + J.KS1;
    int ST = 9 * KS;
    int b = blockIdx.z;
    int t = threadIdx.x, w = t >> 6, l = t & 63, quad = l >> 4, ln = l & 15;
    int pBase = blockIdx.x * 64 + w * 32;

    int padpix[2];
#pragma unroll
    for (int tn = 0; tn < 2; ++tn) {
        int p = pBase + tn * 16 + ln;
        padpix[tn] = ((p >> 6) + 1) * 66 + (p & 63) + 1;
    }
    size_t aoff[2];
#pragma unroll
    for (int tm = 0; tm < 2; ++tm) aoff[tm] = (size_t)(tm * 16 + ln) * 32 + quad * 8;

    const unsigned short* S0H = s0h + (size_t)b * KS0 * PIX66 * 32;
    const unsigned short* S0L = s0l + (size_t)b * KS0 * PIX66 * 32;
    const unsigned short* S1H = J.KS1 ? J.s1h + (size_t)b * PIX66 * 32
                                      : (const unsigned short*)0;
    const unsigned short* S1L = J.KS1 ? J.s1l + (size_t)b * PIX66 * 32
                                      : (const unsigned short*)0;

    f32x4 acc[2][2];
#pragma unroll
    for (int i = 0; i < 2; ++i)
#pragma unroll
        for (int j = 0; j < 2; ++j) acc[i][j] = (f32x4){0.f, 0.f, 0.f, 0.f};

    int tap = 0, kg = 0;
    auto adv = [&]() { if (++kg == KS) { kg = 0; ++tap; } };
    auto loadStep = [&](int ltap, int lkg, short8* bh, short8* bl, short8* ah,
                        short8* al) {
        int d3 = ltap / 3;
        int dpix = (d3 - 1) * 66 + (ltap - d3 * 3 - 1);
        const unsigned short* SpH;
        const unsigned short* SpL;
        long plane;
        if (lkg < KS0) {
            SpH = S0H; SpL = S0L; plane = (long)lkg * PIX66 * 32;
        } else {
            SpH = S1H; SpL = S1L; plane = 0;
        }
#pragma unroll
        for (int tn = 0; tn < 2; ++tn) {
            int pix2 = padpix[tn] + dpix;
            long off = plane + (long)pix2 * 32 + (((quad ^ pxor(pix2)) & 3) << 3);
            bh[tn] = *(const short8*)(SpH + off);
            if (J.split) bl[tn] = *(const short8*)(SpL + off);
        }
        const unsigned short* WTh = J.wth + (size_t)(ltap * KS + lkg) * 32 * 32;
        ah[0] = *(const short8*)(WTh + aoff[0]);
        ah[1] = *(const short8*)(WTh + aoff[1]);
        if (J.split) {
            const unsigned short* WTl = J.wtl + (size_t)(ltap * KS + lkg) * 32 * 32;
            al[0] = *(const short8*)(WTl + aoff[0]);
            al[1] = *(const short8*)(WTl + aoff[1]);
        }
    };

    short8 BH[2][2], AH[2][2], BL[2][2], AL[2][2];
#pragma unroll
    for (int u = 0; u < 2; ++u) { loadStep(tap, kg, BH[u], BL[u], AH[u], AL[u]); adv(); }

    for (int s = 0; s < ST; s += 2) {
#pragma unroll
        for (int u = 0; u < 2; ++u) {
            if (s + u < ST) {
#pragma unroll
                for (int tm = 0; tm < 2; ++tm)
#pragma unroll
                    for (int tn = 0; tn < 2; ++tn) {
                        acc[tm][tn] = __builtin_amdgcn_mfma_f32_16x16x32_bf16(
                            AH[u][tm], BH[u][tn], acc[tm][tn], 0, 0, 0);
                        if (J.split) {
                            acc[tm][tn] = __builtin_amdgcn_mfma_f32_16x16x32_bf16(
                                AL[u][tm], BH[u][tn], acc[tm][tn], 0, 0, 0);
                            acc[tm][tn] = __builtin_amdgcn_mfma_f32_16x16x32_bf16(
                                AH[u][tm], BL[u][tn], acc[tm][tn], 0, 0, 0);
                        }
                    }
                if (s + u + 2 < ST) { loadStep(tap, kg, BH[u], BL[u], AH[u], AL[u]); adv(); }
            }
        }
    }

#pragma unroll
    for (int tm = 0; tm < 2; ++tm) {
#pragma unroll
        for (int r = 0; r < 4; ++r) {
            int oc = tm * 16 + quad * 4 + r;
#pragma unroll
            for (int tn = 0; tn < 2; ++tn) {
                int p = pBase + tn * 16 + ln;
                if (J.mode == 1) {
                    if (oc < 19) {
                        float v = (acc[tm][tn][r] + J.bias[oc]) *
                                  J.mask[((size_t)b * 19 + oc) * HW + p];
                        int ch = J.chBase + oc;
                        J.d1[(size_t)(b * 10 + (ch >> 5)) * (PIX66 * 32) +
                             p32o(padpix[tn], ch & 31)] = f2bf(v);
                    }
                } else {  // mode 2
                    float v = acc[tm][tn][r] + J.bias[oc];
                    unsigned short hi = f2bf(v);
                    J.d1[((size_t)b * HW + p) * 32 + oc] = hi;
                    J.d2[((size_t)b * HW + p) * 32 + oc] = f2bf(v - bf2f(hi));
                }
            }
        }
    }
}

// ---------------------------------------------------------------------------
// K-split LDS-staged MFMA conv (v / comp / out) -> bf16 partials [z][oc][HW].
// ---------------------------------------------------------------------------
struct LJob {
    const unsigned short* src;   // [B][KS][PIX66][32] swizzled
    const unsigned short* wt;    // [9][KS][256][32]
    unsigned short* dstb16;
    int KS;
    int nseg;
    int doSum;
};

__global__ __launch_bounds__(128, 3) void conv_lds(LJob j0, LJob j1, int ocgPerJob,
                                                   float* __restrict__ ybuf) {
    int jy = blockIdx.y;
    LJob J = (jy >= ocgPerJob) ? j1 : j0;
    int ocBase = ((jy >= ocgPerJob) ? jy - ocgPerJob : jy) * 64;
    int z = blockIdx.z;
    int b = z & 1, seg = z >> 1;
    int kgPer = J.KS / J.nseg;
    int kgBeg = seg * kgPer, kgEnd = kgBeg + kgPer;
    int ry = blockIdx.x * 2;
    int t = threadIdx.x, w = t >> 6, l = t & 63, quad = l >> 4, ln = l & 15;

    __shared__ unsigned short sB[2][264 * 32];

    const unsigned short* S = J.src + (size_t)b * J.KS * PIX66 * 32;
    const size_t bStageBase = (size_t)(ry * 66) * 32;

    f32x4 acc[4][4];
#pragma unroll
    for (int i = 0; i < 4; ++i)
#pragma unroll
        for (int j = 0; j < 4; ++j) acc[i][j] = (f32x4){0.f, 0.f, 0.f, 0.f};

    {
        const unsigned short* gB = S + (size_t)kgBeg * PIX66 * 32 + bStageBase;
        for (int i = t; i < 1056; i += 128) gll16(gB + (size_t)i * 8, sB[0] + (size_t)i * 8);
    }

    for (int kg = kgBeg; kg < kgEnd; ++kg) {
        int cur = (kg - kgBeg) & 1;
        __syncthreads();
        if (kg + 1 < kgEnd) {
            const unsigned short* gB = S + (size_t)(kg + 1) * PIX66 * 32 + bStageBase;
            for (int i = t; i < 1056; i += 128)
                gll16(gB + (size_t)i * 8, sB[cur ^ 1] + (size_t)i * 8);
        }
        const unsigned short* sBc = sB[cur];
#pragma unroll
        for (int tap = 0; tap < 9; ++tap) {
            const unsigned short* gA =
                J.wt + ((size_t)(tap * J.KS + kg) * 256 + ocBase) * 32;
            int dy = tap / 3 - 1, dx = tap % 3 - 1;
            int lpBase = (1 + w + dy) * 66 + 1 + dx;
            short8 bf[4], af[4];
#pragma unroll
            for (int tn = 0; tn < 4; ++tn) {
                int lp = lpBase + tn * 16 + ln;
                int P = ry * 66 + lp;
                bf[tn] = *(const short8*)(sBc + (size_t)lp * 32 +
                                          (((quad ^ pxor(P)) & 3) << 3));
            }
#pragma unroll
            for (int tm = 0; tm < 4; ++tm)
                af[tm] = *(const short8*)(gA + (size_t)(tm * 16 + ln) * 32 + quad * 8);
#pragma unroll
            for (int tm = 0; tm < 4; ++tm)
#pragma unroll
                for (int tn = 0; tn < 4; ++tn)
                    acc[tm][tn] = __builtin_amdgcn_mfma_f32_16x16x32_bf16(
                        af[tm], bf[tn], acc[tm][tn], 0, 0, 0);
        }
    }

    int prow = ry + w;
#pragma unroll
    for (int tm = 0; tm < 4; ++tm) {
#pragma unroll
        for (int r = 0; r < 4; ++r) {
            int oc = ocBase + tm * 16 + quad * 4 + r;
            float msum = 0.f;
#pragma unroll
            for (int tn = 0; tn < 4; ++tn) {
                int px = tn * 16 + ln;
                J.dstb16[((size_t)z * 256 + oc) * HW + prow * 64 + px] =
                    f2bf(acc[tm][tn][r]);
                msum += acc[tm][tn][r];
            }
            if (J.doSum) {
#pragma unroll
                for (int off = 8; off; off >>= 1) msum += __shfl_down(msum, off, 16);
                if (ln == 0) atomicAdd(&ybuf[b * 256 + oc], msum);
            }
        }
    }
}

// merged: vt = segsum(pV16)+b_v (key-major swizzled bf16)
//         catN ch0..255 = (segsum(pC16)+b_comp)*sc
__global__ __launch_bounds__(256) void vc_combine(
    const unsigned short* __restrict__ pV, const float* __restrict__ bv,
    unsigned short* __restrict__ vt,
    const unsigned short* __restrict__ pC, const float* __restrict__ bc,
    const float* __restrict__ sc, unsigned short* __restrict__ catN) {
    int idx = blockIdx.x * 256 + threadIdx.x;   // 2*256*4096
    int p = idx & 4095;
    int oc = (idx >> 12) & 255;
    int b = idx >> 20;
    int prow = p >> 6, px = p & 63;
    float v = bf2f(pV[((size_t)b * 256 + oc) * HW + p]) +
              bf2f(pV[((size_t)(2 + b) * 256 + oc) * HW + p]) + bv[oc];
    int jc = ((px >> 3) ^ (oc & 7)) & 7;
    vt[(((size_t)b * 64 + prow) * 256 + oc) * 64 + jc * 8 + (px & 7)] = f2bf(v);
    float c = (bf2f(pC[((size_t)b * 256 + oc) * HW + p]) +
               bf2f(pC[((size_t)(2 + b) * 256 + oc) * HW + p]) + bc[oc]) *
              sc[b * 256 + oc];
    int pix = (prow + 1) * 66 + px + 1;
    catN[(size_t)(b * 24 + (oc >> 5)) * (PIX66 * 32) + p32o(pix, oc & 31)] = f2bf(c);
}

// fp32 out = 4 bf16 segs + bias  (NCHW)
__global__ __launch_bounds__(256) void out_combine(const unsigned short* __restrict__ part,
                                                   const float* __restrict__ bias,
                                                   float* __restrict__ outp) {
    int idx = blockIdx.x * 256 + threadIdx.x;   // 2*256*4096
    int p = idx & 4095;
    int oc = (idx >> 12) & 255;
    int b = idx >> 20;
    float v = bf2f(part[((size_t)(0 + b) * 256 + oc) * HW + p]) +
              bf2f(part[((size_t)(2 + b) * 256 + oc) * HW + p]) +
              bf2f(part[((size_t)(4 + b) * 256 + oc) * HW + p]) +
              bf2f(part[((size_t)(6 + b) * 256 + oc) * HW + p]) + bias[oc];
    outp[((size_t)b * 256 + oc) * HW + p] = v;
}

// ---------------------------------------------------------------------------
// Flash attention v3 internals, key-split NSEG=2; partial O as bf16.
// ---------------------------------------------------------------------------
__global__ __launch_bounds__(512, 4) void flash_attn(
    const unsigned short* __restrict__ qt_h, const unsigned short* __restrict__ qt_l,
    const unsigned short* __restrict__ kt_h, const unsigned short* __restrict__ kt_l,
    const unsigned short* __restrict__ vt,
    unsigned short* __restrict__ pO, float* __restrict__ pm, float* __restrict__ pl) {
    int seg = blockIdx.y >> 1, mode = blockIdx.y & 1, b = blockIdx.z;
    size_t qkoff = (size_t)b * HW * 32;
    const unsigned short* Qh = (mode ? kt_h : qt_h) + qkoff;
    const unsigned short* Ql = (mode ? kt_l : qt_l) + qkoff;
    const unsigned short* Kh = (mode ? qt_h : kt_h) + qkoff;
    const unsigned short* Kl = (mode ? qt_l : kt_l) + qkoff;
    const unsigned short* Vt = vt + (size_t)b * 64 * 256 * 64;

    int t = threadIdx.x, w = t >> 6, l = t & 63, quad = l >> 4, ln = l & 15;
    int pg = w & 1, ch = w >> 1;
    int p0 = blockIdx.x * 64, pw = pg * 32;
    int cb = ch * 64;
    bool soft = (ch == (pg ? 3 : 0));

    __shared__ unsigned short sV[256 * 64];
    __shared__ unsigned short sP[64 * 68];
    __shared__ float sAl[64];

    short8 qbh[2], qbl[2];
    if (soft) {
#pragma unroll
        for (int pn = 0; pn < 2; ++pn) {
            size_t off = (size_t)(p0 + pw + pn * 16 + ln) * 32 + quad * 8;
            qbh[pn] = *(const short8*)(Qh + off);
            qbl[pn] = *(const short8*)(Ql + off);
        }
    }

    float m_run[2] = {-3.0e38f, -3.0e38f};
    float l_run[2] = {0.f, 0.f};
    f32x4 accO[4][2];
#pragma unroll
    for (int cs = 0; cs < 4; ++cs)
#pragma unroll
        for (int pn = 0; pn < 2; ++pn) accO[cs][pn] = (f32x4){0.f, 0.f, 0.f, 0.f};

    int jbBeg = seg * (HW / 2);
    for (int jb = jbBeg; jb < jbBeg + HW / 2; jb += 64) {
        __syncthreads();
        {
            const unsigned short* gV = Vt + (size_t)(jb >> 6) * (256 * 64);
#pragma unroll
            for (int i = 0; i < 4; ++i)
                gll16(gV + (size_t)(t + 512 * i) * 8, sV + (size_t)(t + 512 * i) * 8);
        }
        if (soft) {
            f32x4 sacc[2][4];
#pragma unroll
            for (int pn = 0; pn < 2; ++pn)
#pragma unroll
                for (int jj = 0; jj < 4; ++jj) sacc[pn][jj] = (f32x4){0.f, 0.f, 0.f, 0.f};
#pragma unroll
            for (int jj = 0; jj < 4; ++jj) {
                size_t off = (size_t)(jb + 16 * jj + ln) * 32 + quad * 8;
                short8 kh = *(const short8*)(Kh + off);
                short8 kr = *(const short8*)(Kl + off);
#pragma unroll
                for (int pn = 0; pn < 2; ++pn) {
                    sacc[pn][jj] = __builtin_amdgcn_mfma_f32_16x16x32_bf16(
                        kh, qbh[pn], sacc[pn][jj], 0, 0, 0);
                    sacc[pn][jj] = __builtin_amdgcn_mfma_f32_16x16x32_bf16(
                        kh, qbl[pn], sacc[pn][jj], 0, 0, 0);
                    sacc[pn][jj] = __builtin_amdgcn_mfma_f32_16x16x32_bf16(
                        kr, qbh[pn], sacc[pn][jj], 0, 0, 0);
                }
            }
#pragma unroll
            for (int pn = 0; pn < 2; ++pn) {
                float tmx = -3.0e38f;
#pragma unroll
                for (int jj = 0; jj < 4; ++jj)
#pragma unroll
                    for (int r = 0; r < 4; ++r) tmx = fmaxf(tmx, sacc[pn][jj][r]);
                tmx = fmaxf(tmx, __shfl_xor(tmx, 16));
                tmx = fmaxf(tmx, __shfl_xor(tmx, 32));
                float mnew = fmaxf(m_run[pn], tmx);
                float alpha = __expf(m_run[pn] - mnew);
                m_run[pn] = mnew;
                float psum = 0.f;
#pragma unroll
                for (int jj = 0; jj < 4; ++jj) {
                    float e0 = __expf(sacc[pn][jj][0] - mnew);
                    float e1 = __expf(sacc[pn][jj][1] - mnew);
                    float e2 = __expf(sacc[pn][jj][2] - mnew);
                    float e3 = __expf(sacc[pn][jj][3] - mnew);
                    psum += (e0 + e1) + (e2 + e3);
                    uint2 pk;
                    pk.x = pkbf(e0, e1);
                    pk.y = pkbf(e2, e3);
                    *(uint2*)(sP + (size_t)(pw + pn * 16 + ln) * 68 + jj * 16 +
                              quad * 4) = pk;
                }
                psum += __shfl_xor(psum, 16);
                psum += __shfl_xor(psum, 32);
                l_run[pn] = l_run[pn] * alpha + psum;
                if (quad == 0) sAl[pw + pn * 16 + ln] = alpha;
            }
        }
        __syncthreads();
        float al0 = sAl[pw + ln];
        float al1 = sAl[pw + 16 + ln];
#pragma unroll
        for (int cs = 0; cs < 4; ++cs) { accO[cs][0] *= al0; accO[cs][1] *= al1; }
#pragma unroll
        for (int j2 = 0; j2 < 2; ++j2) {
            short8 pb0 = *(const short8*)(sP + (size_t)(pw + ln) * 68 + j2 * 32 +
                                          quad * 8);
            short8 pb1 = *(const short8*)(sP + (size_t)(pw + 16 + ln) * 68 + j2 * 32 +
                                          quad * 8);
#pragma unroll
            for (int cs = 0; cs < 4; ++cs) {
                int c = cb + cs * 16 + ln;
                short8 va = *(const short8*)(
                    sV + (size_t)c * 64 + ((((j2 * 4 + quad) ^ (c & 7)) & 7) << 3));
                accO[cs][0] = __builtin_amdgcn_mfma_f32_16x16x32_bf16(
                    va, pb0, accO[cs][0], 0, 0, 0);
                accO[cs][1] = __builtin_amdgcn_mfma_f32_16x16x32_bf16(
                    va, pb1, accO[cs][1], 0, 0, 0);
            }
        }
    }

    int idx4 = (seg * 2 + mode) * 2 + b;
#pragma unroll
    for (int pn = 0; pn < 2; ++pn) {
        int p = p0 + pw + pn * 16 + ln;
        if (soft && quad == 0) {
            pm[(size_t)idx4 * HW + p] = m_run[pn];
            pl[(size_t)idx4 * HW + p] = l_run[pn];
        }
#pragma unroll
        for (int cs = 0; cs < 4; ++cs)
#pragma unroll
            for (int r = 0; r < 4; ++r) {
                int c = cb + cs * 16 + quad * 4 + r;
                pO[((size_t)idx4 * 256 + c) * HW + p] = f2bf(accO[cs][pn][r]);
            }
    }
}

// combine two key-segments (bf16 partials) -> catN ch 256+mode*256..
__global__ __launch_bounds__(256) void attn_combine(const unsigned short* __restrict__ pO,
                                                    const float* __restrict__ pm,
                                                    const float* __restrict__ pl,
                                                    unsigned short* __restrict__ catN) {
    int b = blockIdx.z, mode = blockIdx.y;
    int t = threadIdx.x;
    int p = blockIdx.x * 64 + (t & 63);
    int c0 = (t >> 6) * 64;
    int i0 = mode * 2 + b;
    int i1 = 4 + mode * 2 + b;
    float m0 = pm[(size_t)i0 * HW + p], m1 = pm[(size_t)i1 * HW + p];
    float l0 = pl[(size_t)i0 * HW + p], l1 = pl[(size_t)i1 * HW + p];
    float M = fmaxf(m0, m1);
    float e0 = __expf(m0 - M), e1 = __expf(m1 - M);
    float inv = 1.f / (l0 * e0 + l1 * e1);
    e0 *= inv;
    e1 *= inv;
    int y = p >> 6, x = p & 63;
    int pix = (y + 1) * 66 + x + 1;
    for (int c = c0; c < c0 + 64; ++c) {
        float v = bf2f(pO[((size_t)i0 * 256 + c) * HW + p]) * e0 +
                  bf2f(pO[((size_t)i1 * 256 + c) * HW + p]) * e1;
        int cf = 256 + mode * 256 + c;
        catN[(size_t)(b * 24 + (cf >> 5)) * (PIX66 * 32) + p32o(pix, cf & 31)] = f2bf(v);
    }
}

// ---------------------------------------------------------------------------
// SE mlp (bias folded: y = rawsum/4096 + b_comp)
// ---------------------------------------------------------------------------
__global__ __launch_bounds__(256) void se_mlp_kernel(const float* __restrict__ y,
                                                     const float* __restrict__ bcomp,
                                                     const float* __restrict__ w1,
                                                     const float* __restrict__ w2,
                                                     float* __restrict__ sc) {
    int b = blockIdx.x, t = threadIdx.x;
    __shared__ float sy[256], sh[32];
    sy[t] = y[b * 256 + t] * (1.f / 4096.f) + bcomp[t];
    __syncthreads();
    if (t < 32) {
        float s = 0.f;
        for (int c = 0; c < 256; ++c) s = fmaf(w1[t * 256 + c], sy[c], s);
        sh[t] = fmaxf(s, 0.f);
    }
    __syncthreads();
    float s = 0.f;
#pragma unroll
    for (int h = 0; h < 32; ++h) s = fmaf(w2[t * 32 + h], sh[h], s);
    sc[b * 256 + t] = 1.f / (1.f + __expf(-s));
}

// ---------------------------------------------------------------------------
extern "C" void kernel_launch(void* const* d_in, const int* in_sizes, int n_in,
                              void* d_out, int out_size, void* d_ws, size_t ws_size,
                              hipStream_t stream) {
    const float* x      = (const float*)d_in[0];
    const float* mmask  = (const float*)d_in[1];
    const float* amask  = (const float*)d_in[2];
    const float* w_mp   = (const float*)d_in[3];
    const float* b_mp   = (const float*)d_in[4];
    const float* w_ap   = (const float*)d_in[5];
    const float* b_ap   = (const float*)d_in[6];
    const float* w_q    = (const float*)d_in[7];
    const float* b_q    = (const float*)d_in[8];
    const float* w_k    = (const float*)d_in[9];
    const float* b_k    = (const float*)d_in[10];
    const float* w_v    = (const float*)d_in[11];
    const float* b_v    = (const float*)d_in[12];
    const float* w_comp = (const float*)d_in[13];
    const float* b_comp = (const float*)d_in[14];
    const float* w_out  = (const float*)d_in[15];
    const float* b_out  = (const float*)d_in[16];
    const float* w_se1  = (const float*)d_in[17];
    const float* w_se2  = (const float*)d_in[18];

    unsigned short* us = (unsigned short*)d_ws;
    size_t o = 0;
    // ---- zeroed bf16 region (swizzled P32 padded buffers) ----
    unsigned short* xpad_hi = us + o; o += (size_t)2 * 8 * PIX66 * 32;
    unsigned short* xpad_lo = us + o; o += (size_t)2 * 8 * PIX66 * 32;
    unsigned short* mq_hi   = us + o; o += (size_t)2 * PIX66 * 32;
    unsigned short* mq_lo   = us + o; o += (size_t)2 * PIX66 * 32;
    unsigned short* ma_hi   = us + o; o += (size_t)2 * PIX66 * 32;
    unsigned short* ma_lo   = us + o; o += (size_t)2 * PIX66 * 32;
    unsigned short* ipad    = us + o; o += (size_t)2 * 10 * PIX66 * 32;
    unsigned short* catN    = us + o; o += (size_t)2 * 24 * PIX66 * 32;
    size_t zeroBytes = o * sizeof(unsigned short);
    // ---- fully-written bf16 region ----
    unsigned short* wt_mp = us + o; o += (size_t)9 * 8 * 32 * 32;
    unsigned short* wt_ap = us + o; o += (size_t)9 * 8 * 32 * 32;
    unsigned short* wt_qh = us + o; o += (size_t)9 * 9 * 32 * 32;
    unsigned short* wt_ql = us + o; o += (size_t)9 * 9 * 32 * 32;
    unsigned short* wt_kh = us + o; o += (size_t)9 * 9 * 32 * 32;
    unsigned short* wt_kl = us + o; o += (size_t)9 * 9 * 32 * 32;
    unsigned short* wt_v  = us + o; o += (size_t)9 * 8 * 256 * 32;
    unsigned short* wt_cp = us + o; o += (size_t)9 * 10 * 256 * 32;
    unsigned short* wt_ot = us + o; o += (size_t)9 * 24 * 256 * 32;
    unsigned short* qt_h  = us + o; o += (size_t)2 * HW * 32;
    unsigned short* qt_l  = us + o; o += (size_t)2 * HW * 32;
    unsigned short* kt_h  = us + o; o += (size_t)2 * HW * 32;
    unsigned short* kt_l  = us + o; o += (size_t)2 * HW * 32;
    unsigned short* vt    = us + o; o += (size_t)2 * 64 * 256 * 64;
    unsigned short* pV16  = us + o; o += (size_t)4 * 256 * HW;
    unsigned short* pC16  = us + o; o += (size_t)4 * 256 * HW;
    unsigned short* pA16  = us + o; o += (size_t)8 * 256 * HW;
    unsigned short* pO16  = us + o; o += (size_t)8 * 256 * HW;
    // ---- fp32 region (fully written before read) ----
    float* fp = (float*)(us + o);
    size_t fo = 0;
    float* pmb  = fp + fo; fo += (size_t)8 * HW;
    float* plb  = fp + fo; fo += (size_t)8 * HW;
    float* ybuf = fp + fo; fo += 512;
    float* sbuf = fp + fo; fo += 512;
    size_t need = o * sizeof(unsigned short) + fo * sizeof(float);
    if (ws_size < need) return;

    float* outp = (float*)d_out;

    hipMemsetAsync(us, 0, zeroBytes, stream);
    hipMemsetAsync(ybuf, 0, 512 * sizeof(float), stream);

    // fused weight transforms
    WtJob W0{w_mp,   wt_mp, (unsigned short*)0, 19, 32, 256, 256, 0, 256};
    WtJob W1{w_ap,   wt_ap, (unsigned short*)0, 19, 32, 256, 256, 0, 256};
    WtJob W2{w_q,    wt_qh, wt_ql,             32, 32, 256, 256, 19, 288};
    WtJob W3{w_k,    wt_kh, wt_kl,             32, 32, 256, 256, 19, 288};
    WtJob W4{w_v,    wt_v,  (unsigned short*)0, 256, 256, 256, 256, 0, 256};
    WtJob W5{w_comp, wt_cp, (unsigned short*)0, 256, 256, 294, 320, 0, 320};
    WtJob W6{w_out,  wt_ot, (unsigned short*)0, 256, 256, 768, 768, 0, 768};
    k_wt_all<<<dim3((9 * 24 * 256 * 32 + 255) / 256, 7), 256, 0, stream>>>(
        W0, W1, W2, W3, W4, W5, W6);

    k_build_x<<<dim3(64, 4, 2), 256, 0, stream>>>(x, xpad_hi, xpad_lo, ipad);
    k_build_mask2<<<dim3(1024, 2), 256, 0, stream>>>(mmask, amask, mq_hi, mq_lo,
                                                     ma_hi, ma_lo);

    const unsigned short* NUS = (const unsigned short*)0;
    unsigned short* NUSo = (unsigned short*)0;
    float* NF = (float*)0;

    // mp+ap+q+k in one dispatch
    DJob dm{NUS, NUS, wt_mp, NUS, b_mp, ipad, NUSo, mmask, 256, 1, 0, 0};
    DJob da{NUS, NUS, wt_ap, NUS, b_ap, ipad, NUSo, amask, 275, 1, 0, 0};
    DJob dq{mq_hi, mq_lo, wt_qh, wt_ql, b_q, qt_h, qt_l, NF, 0, 2, 1, 1};
    DJob dk{ma_hi, ma_lo, wt_kh, wt_kl, b_k, kt_h, kt_l, NF, 0, 2, 1, 1};
    conv_direct_all<<<dim3(64, 4, 2), 128, 0, stream>>>(xpad_hi, xpad_lo, dm, da, dq, dk);

    // v + comp, K-split x2 -> bf16 partials (1024 blocks)
    LJob lv{xpad_hi, wt_v, pV16, 8, 2, 0};
    LJob lc{ipad, wt_cp, pC16, 10, 2, 1};
    conv_lds<<<dim3(32, 8, 4), 128, 0, stream>>>(lv, lc, 4, ybuf);

    // SE (bias folded) + merged v/comp combine (bf16 partial reads)
    se_mlp_kernel<<<2, 256, 0, stream>>>(ybuf, b_comp, w_se1, w_se2, sbuf);
    vc_combine<<<8192, 256, 0, stream>>>(pV16, b_v, vt, pC16, b_comp, sbuf, catN);

    // flash attention (v3 internals), key-split NSEG=2, bf16 partial O
    flash_attn<<<dim3(64, 4, 2), 512, 0, stream>>>(qt_h, qt_l, kt_h, kt_l, vt,
                                                   pA16, pmb, plb);
    attn_combine<<<dim3(64, 2, 2), 256, 0, stream>>>(pA16, pmb, plb, catN);

    // final conv, K-split x4 -> bf16 partials (1024 blocks) + combine
    LJob lo{catN, wt_ot, pO16, 24, 4, 0};
    conv_lds<<<dim3(32, 4, 8), 128, 0, stream>>>(lo, lo, 4, NF);
    out_combine<<<8192, 256, 0, stream>>>(pO16, b_out, outp);
}